// Round 5
// baseline (244.166 us; speedup 1.0000x reference)
//
#include <hip/hip_runtime.h>

#define N_NODES 50000
#define N_EDGES 800000
#define D_IN    256
#define D_OUT   128
#define EPS     1e-9f
#define CAP     64      // max edges/row (avg deg 16, Poisson tail P(>64) ~ 1e-19)
#define PAD     88      // LDS k-stride in ushorts: 176B rows, 16B-aligned b128

typedef __attribute__((ext_vector_type(8))) short bf16x8;   // MFMA A/B frag (4 VGPRs)
typedef __attribute__((ext_vector_type(4))) float floatx4;  // MFMA C/D frag

__device__ __forceinline__ ushort f2bf(float x) {           // RTNE fp32 -> bf16
    unsigned u = __float_as_uint(x);
    u += 0x7fffu + ((u >> 16) & 1u);
    return (ushort)(u >> 16);
}

// ---------------------------------------------------------------------------
// prep: (a) Xb = bf16(feat) [50000x256]  (b) Wb[n][k] = bf16 transposed [W0|W1]
// ---------------------------------------------------------------------------
#define PREP_XB_BLOCKS  6250   // 12.8M elems / (256 thr * 8 elem)
#define PREP_WB_BLOCKS  32
__global__ __launch_bounds__(256) void prep(
    const float* __restrict__ feat, const float* __restrict__ W0,
    const float* __restrict__ W1, ushort* __restrict__ Xb,
    ushort* __restrict__ Wb)
{
    int bid = blockIdx.x;
    int t   = threadIdx.x;
    if (bid < PREP_XB_BLOCKS) {
        size_t g = (size_t)bid * 256 + t;       // 8-elem group
        const float* p = &feat[g * 8];
        float4 v0 = *(const float4*)p;
        float4 v1 = *(const float4*)(p + 4);
        union { ushort us[8]; uint4 v; } tmp;
        tmp.us[0] = f2bf(v0.x); tmp.us[1] = f2bf(v0.y);
        tmp.us[2] = f2bf(v0.z); tmp.us[3] = f2bf(v0.w);
        tmp.us[4] = f2bf(v1.x); tmp.us[5] = f2bf(v1.y);
        tmp.us[6] = f2bf(v1.z); tmp.us[7] = f2bf(v1.w);
        *(uint4*)&Xb[g * 8] = tmp.v;
    } else {
        int g  = (bid - PREP_XB_BLOCKS) * 256 + t;
        int n  = g >> 5;                        // 0..255
        int kq = g & 31;                        // 8-elem k group
        const float* W = (n < 128) ? W0 : W1;
        int nn = n & 127;
        union { ushort us[8]; uint4 v; } tmp;
#pragma unroll
        for (int j = 0; j < 8; ++j)
            tmp.us[j] = f2bf(W[(size_t)(kq * 8 + j) * D_OUT + nn]);
        *(uint4*)&Wb[(size_t)n * D_IN + kq * 8] = tmp.v;
    }
}

// ---------------------------------------------------------------------------
// Fused bf16 MFMA GEMM + edge-bucket scatter prologue.
//   Prologue: each block scatters its ~1024-edge slice into (cnt, slot2);
//   the scatter is latency-bound and drains in the shadow of the MFMA K-loop.
//   cnt must be zeroed beforehand (hipMemsetAsync).
//   blockIdx.y==0: cols 0..127  -> bias0+relu+LayerNorm -> out[:, 0:128]
//   blockIdx.y==1: cols 128..255 -> raw bf16 -> Y1[M,128]
// 128x128 tile/block, 4 waves, BK=64. 16x16x32 layouts (HW-verified):
// A[m=lane&15][k=quad*8+j], B[k=quad*8+j][n=lane&15], D[row=quad*4+reg][col=lane&15].
// ---------------------------------------------------------------------------
__global__ __launch_bounds__(256, 2) void gemm_mfma(
    const ushort* __restrict__ Xb, const ushort* __restrict__ Wb,
    const float* __restrict__ bias, const float* __restrict__ scale,
    const float* __restrict__ offset,
    float* __restrict__ out, ushort* __restrict__ Y1,
    const int* __restrict__ er, const int* __restrict__ ec,
    const float* __restrict__ ev, int* __restrict__ cnt,
    int2* __restrict__ slot2)
{
    __shared__ ushort As[128 * PAD];
    __shared__ ushort Bs[128 * PAD];

    const int t    = threadIdx.x;
    const int wave = t >> 6, lane = t & 63;
    const int quad = lane >> 4, l16 = lane & 15;
    const int m0   = blockIdx.x * 128;
    const int n0   = blockIdx.y * 128;

    // ---- edge-scatter prologue (independent of gemm; hides under MFMA) ----
    {
        int bid   = blockIdx.y * gridDim.x + blockIdx.x;   // 0..781
        int ebase = bid * 1024;
#pragma unroll
        for (int u = 0; u < 4; ++u) {
            int e = ebase + u * 256 + t;
            if (e < N_EDGES) {
                int   r = er[e];
                int   c = ec[e];
                float v = ev[e];
                int pos = atomicAdd(&cnt[r], 1);
                if (pos < CAP)
                    slot2[(size_t)r * CAP + pos] = make_int2(c, __float_as_int(v));
            }
        }
    }

    floatx4 acc[2][8];
#pragma unroll
    for (int mt = 0; mt < 2; ++mt)
#pragma unroll
        for (int nt = 0; nt < 8; ++nt)
            acc[mt][nt] = (floatx4){0.f, 0.f, 0.f, 0.f};

    for (int kt = 0; kt < D_IN; kt += 64) {
        // ---- stage A (128 rows x 64 k) straight bf16 uint4 copies ----
#pragma unroll
        for (int i = 0; i < 4; ++i) {
            int g = t + i * 256;          // 0..1023 (16B groups)
            int row = g >> 3, kq = g & 7;
            int grow = m0 + row;
            uint4 v = make_uint4(0u, 0u, 0u, 0u);
            if (grow < N_NODES)
                v = *(const uint4*)&Xb[(size_t)grow * D_IN + kt + kq * 8];
            *(uint4*)&As[row * PAD + kq * 8] = v;
        }
        // ---- stage B (128 n-rows x 64 k) from Wb[n][k] ----
#pragma unroll
        for (int i = 0; i < 4; ++i) {
            int g = t + i * 256;
            int row = g >> 3, kq = g & 7;
            *(uint4*)&Bs[row * PAD + kq * 8] =
                *(const uint4*)&Wb[(size_t)(n0 + row) * D_IN + kt + kq * 8];
        }
        __syncthreads();

#pragma unroll
        for (int kk = 0; kk < 64; kk += 32) {
            bf16x8 a[2], b[8];
#pragma unroll
            for (int mt = 0; mt < 2; ++mt)
                a[mt] = *(bf16x8*)&As[(wave * 32 + mt * 16 + l16) * PAD + kk + quad * 8];
#pragma unroll
            for (int nt = 0; nt < 8; ++nt)
                b[nt] = *(bf16x8*)&Bs[(nt * 16 + l16) * PAD + kk + quad * 8];
#pragma unroll
            for (int mt = 0; mt < 2; ++mt)
#pragma unroll
                for (int nt = 0; nt < 8; ++nt)
                    acc[mt][nt] = __builtin_amdgcn_mfma_f32_16x16x32_bf16(
                        a[mt], b[nt], acc[mt][nt], 0, 0, 0);
        }
        __syncthreads();
    }

    if (blockIdx.y == 0) {
        float bb[8], sc[8], of[8];
#pragma unroll
        for (int nt = 0; nt < 8; ++nt) {
            bb[nt] = bias[nt * 16 + l16];
            sc[nt] = scale[nt * 16 + l16];
            of[nt] = offset[nt * 16 + l16];
        }
#pragma unroll
        for (int mt = 0; mt < 2; ++mt)
#pragma unroll
            for (int i = 0; i < 4; ++i) {
                float h[8], s = 0.f, q = 0.f;
#pragma unroll
                for (int nt = 0; nt < 8; ++nt) {
                    h[nt] = fmaxf(acc[mt][nt][i] + bb[nt], 0.f);
                    s += h[nt];
                    q += h[nt] * h[nt];
                }
#pragma unroll
                for (int m = 1; m < 16; m <<= 1) {
                    s += __shfl_xor(s, m);
                    q += __shfl_xor(q, m);
                }
                float mean = s * (1.f / 128.f);
                float inv  = rsqrtf(q * (1.f / 128.f) - mean * mean + EPS);
                int row = m0 + wave * 32 + mt * 16 + quad * 4 + i;
                if (row < N_NODES) {
#pragma unroll
                    for (int nt = 0; nt < 8; ++nt)
                        out[(size_t)row * 256 + nt * 16 + l16] =
                            (h[nt] - mean) * sc[nt] * inv + of[nt];
                }
            }
    } else {
#pragma unroll
        for (int mt = 0; mt < 2; ++mt)
#pragma unroll
            for (int i = 0; i < 4; ++i) {
                int row = m0 + wave * 32 + mt * 16 + quad * 4 + i;
                if (row < N_NODES) {
#pragma unroll
                    for (int nt = 0; nt < 8; ++nt)
                        Y1[(size_t)row * D_OUT + nt * 16 + l16] =
                            f2bf(acc[mt][nt][i]);
                }
            }
    }
}

// ---------------------------------------------------------------------------
// Fused gather-SpMM (bf16 Y) + bias + relu + LayerNorm -> out[:, 128:256].
// One wave per row; lane l owns cols {2l, 2l+1}. Edge loop unrolled x8 so
// 8 independent 256B row-gathers are in flight per wave (latency hiding).
// ---------------------------------------------------------------------------
__global__ __launch_bounds__(256) void spmm_gather_ln(
    const int* __restrict__ cnt, const int2* __restrict__ slot2,
    const ushort* __restrict__ Y,
    const float* __restrict__ bias, const float* __restrict__ scale,
    const float* __restrict__ offset, float* __restrict__ out)
{
    int row  = blockIdx.x * 4 + (threadIdx.x >> 6);
    int lane = threadIdx.x & 63;
    if (row >= N_NODES) return;

    int n = cnt[row];
    n = n < CAP ? n : CAP;

    int   c = 0;
    float v = 0.f;
    if (lane < n) {
        int2 p = slot2[(size_t)row * CAP + lane];
        c = p.x;
        v = __int_as_float(p.y);
    }

    float ax = 0.f, ay = 0.f;
    int j = 0;
    for (; j + 8 <= n; j += 8) {
        unsigned yv[8]; float vv[8];
#pragma unroll
        for (int u = 0; u < 8; ++u) {
            int cj = __shfl(c, j + u);
            vv[u]  = __shfl(v, j + u);
            yv[u]  = *(const unsigned*)&Y[(size_t)cj * D_OUT + lane * 2];
        }
#pragma unroll
        for (int u = 0; u < 8; ++u) {
            ax = fmaf(vv[u], __uint_as_float(yv[u] << 16), ax);
            ay = fmaf(vv[u], __uint_as_float(yv[u] & 0xffff0000u), ay);
        }
    }
    for (; j < n; ++j) {
        int   cj = __shfl(c, j);
        float vj = __shfl(v, j);
        unsigned yv = *(const unsigned*)&Y[(size_t)cj * D_OUT + lane * 2];
        ax = fmaf(vj, __uint_as_float(yv << 16), ax);
        ay = fmaf(vj, __uint_as_float(yv & 0xffff0000u), ay);
    }

    int cidx = lane * 2;
    float h0 = fmaxf(ax + bias[cidx + 0], 0.f);
    float h1 = fmaxf(ay + bias[cidx + 1], 0.f);
    float s = h0 + h1, q = h0 * h0 + h1 * h1;
#pragma unroll
    for (int m = 1; m < 64; m <<= 1) {
        s += __shfl_xor(s, m);
        q += __shfl_xor(q, m);
    }
    float mean = s * (1.f / 128.f);
    float var  = q * (1.f / 128.f) - mean * mean + EPS;
    float inv  = rsqrtf(var);
    float2 o;
    o.x = (h0 - mean) * scale[cidx + 0] * inv + offset[cidx + 0];
    o.y = (h1 - mean) * scale[cidx + 1] * inv + offset[cidx + 1];
    *(float2*)&out[(size_t)row * 256 + 128 + cidx] = o;
}

extern "C" void kernel_launch(void* const* d_in, const int* in_sizes, int n_in,
                              void* d_out, int out_size, void* d_ws, size_t ws_size,
                              hipStream_t stream)
{
    const float* feat = (const float*)d_in[0];
    const float* W0   = (const float*)d_in[1];
    const float* b0   = (const float*)d_in[2];
    const float* s0   = (const float*)d_in[3];
    const float* o0   = (const float*)d_in[4];
    const float* W1   = (const float*)d_in[5];
    const float* b1   = (const float*)d_in[6];
    const float* s1   = (const float*)d_in[7];
    const float* o1   = (const float*)d_in[8];
    const int*   er   = (const int*)d_in[9];
    const int*   ec   = (const int*)d_in[10];
    const float* ev   = (const float*)d_in[11];
    float* out = (float*)d_out;

    // workspace layout (all 16B-aligned offsets), total ~64.3 MB
    char*   wsb   = (char*)d_ws;
    ushort* Xb    = (ushort*)(wsb);                 // 25,600,000 B
    ushort* Wb    = (ushort*)(wsb + 25600000);      //    131,072 B
    ushort* Y1    = (ushort*)(wsb + 25731072);      // 12,800,000 B
    int*    cnt   = (int*)   (wsb + 38531072);      //    200,000 B
    int2*   slot2 = (int2*)  (wsb + 38731072);      // 25,600,000 B

    hipMemsetAsync(cnt, 0, (size_t)N_NODES * sizeof(int), stream);

    prep<<<PREP_XB_BLOCKS + PREP_WB_BLOCKS, 256, 0, stream>>>(
        feat, W0, W1, Xb, Wb);

    gemm_mfma<<<dim3((N_NODES + 127) / 128, 2), 256, 0, stream>>>(
        Xb, Wb, b0, s0, o0, out, Y1, er, ec, ev, cnt, slot2);

    spmm_gather_ln<<<(N_NODES + 3) / 4, 256, 0, stream>>>(
        cnt, slot2, Y1, b1, s1, o1, out);
}

// Round 6
// 217.960 us; speedup vs baseline: 1.1202x; 1.1202x over previous
//
#include <hip/hip_runtime.h>

#define N_NODES 50000
#define N_EDGES 800000
#define D_IN    256
#define D_OUT   128
#define EPS     1e-9f
#define CAP     64      // max edges/row (avg deg 16, Poisson tail P(>64) ~ 1e-19)
#define PAD     88      // LDS k-stride in ushorts: 176B rows, 16B-aligned b128
#define CNT_STRIDE 16   // one row-counter per 64B cache line (kills line contention)

typedef __attribute__((ext_vector_type(8))) short bf16x8;   // MFMA A/B frag (4 VGPRs)
typedef __attribute__((ext_vector_type(4))) float floatx4;  // MFMA C/D frag

__device__ __forceinline__ ushort f2bf(float x) {           // RTNE fp32 -> bf16
    unsigned u = __float_as_uint(x);
    u += 0x7fffu + ((u >> 16) & 1u);
    return (ushort)(u >> 16);
}

// ---------------------------------------------------------------------------
// prep_build: block-role split in one kernel (no barriers, no LDS -> all
// roles co-resident; scatter role is atomic-latency-bound, prep roles are
// BW-bound -> they overlap on different pipes).
//   role 0 (bid < 782):   scatter 1024 edges/block into (cnt, slot2)
//   role 1 (next 6250):   Xb = bf16(feat)
//   role 2 (last 32):     Wb[n][k] = bf16 transposed [W0|W1]
// cnt must be zeroed beforehand (hipMemsetAsync), padded CNT_STRIDE.
// ---------------------------------------------------------------------------
#define BUILD_BLOCKS    782    // 782 * 1024 = 800768 >= 800000
#define PREP_XB_BLOCKS  6250   // 12.8M elems / (256 thr * 8 elem)
#define PREP_WB_BLOCKS  32
__global__ __launch_bounds__(256) void prep_build(
    const float* __restrict__ feat, const float* __restrict__ W0,
    const float* __restrict__ W1, ushort* __restrict__ Xb,
    ushort* __restrict__ Wb,
    const int* __restrict__ er, const int* __restrict__ ec,
    const float* __restrict__ ev, int* __restrict__ cnt,
    int2* __restrict__ slot2)
{
    int bid = blockIdx.x;
    int t   = threadIdx.x;
    if (bid < BUILD_BLOCKS) {
        int ebase = bid * 1024;
#pragma unroll
        for (int u = 0; u < 4; ++u) {
            int e = ebase + u * 256 + t;
            if (e < N_EDGES) {
                int   r = er[e];
                int   c = ec[e];
                float v = ev[e];
                int pos = atomicAdd(&cnt[r * CNT_STRIDE], 1);
                if (pos < CAP)
                    slot2[(size_t)r * CAP + pos] = make_int2(c, __float_as_int(v));
            }
        }
    } else if (bid < BUILD_BLOCKS + PREP_XB_BLOCKS) {
        size_t g = (size_t)(bid - BUILD_BLOCKS) * 256 + t;   // 8-elem group
        const float* p = &feat[g * 8];
        float4 v0 = *(const float4*)p;
        float4 v1 = *(const float4*)(p + 4);
        union { ushort us[8]; uint4 v; } tmp;
        tmp.us[0] = f2bf(v0.x); tmp.us[1] = f2bf(v0.y);
        tmp.us[2] = f2bf(v0.z); tmp.us[3] = f2bf(v0.w);
        tmp.us[4] = f2bf(v1.x); tmp.us[5] = f2bf(v1.y);
        tmp.us[6] = f2bf(v1.z); tmp.us[7] = f2bf(v1.w);
        *(uint4*)&Xb[g * 8] = tmp.v;
    } else {
        int g  = (bid - BUILD_BLOCKS - PREP_XB_BLOCKS) * 256 + t;
        int n  = g >> 5;                        // 0..255
        int kq = g & 31;                        // 8-elem k group
        const float* W = (n < 128) ? W0 : W1;
        int nn = n & 127;
        union { ushort us[8]; uint4 v; } tmp;
#pragma unroll
        for (int j = 0; j < 8; ++j)
            tmp.us[j] = f2bf(W[(size_t)(kq * 8 + j) * D_OUT + nn]);
        *(uint4*)&Wb[(size_t)n * D_IN + kq * 8] = tmp.v;
    }
}

// ---------------------------------------------------------------------------
// Fused bf16 MFMA GEMM: C = Xb[M,256] @ Wb^T  (N=256 in two halves)
//   blockIdx.y==0: cols 0..127  -> bias0+relu+LayerNorm -> out[:, 0:128]
//   blockIdx.y==1: cols 128..255 -> raw bf16 -> Y1[M,128]
// 128x128 tile/block, 4 waves, BK=64. 16x16x32 layouts (HW-verified):
// A[m=lane&15][k=quad*8+j], B[k=quad*8+j][n=lane&15], D[row=quad*4+reg][col=lane&15].
// ---------------------------------------------------------------------------
__global__ __launch_bounds__(256, 2) void gemm_mfma(
    const ushort* __restrict__ Xb, const ushort* __restrict__ Wb,
    const float* __restrict__ bias, const float* __restrict__ scale,
    const float* __restrict__ offset,
    float* __restrict__ out, ushort* __restrict__ Y1)
{
    __shared__ ushort As[128 * PAD];
    __shared__ ushort Bs[128 * PAD];

    const int t    = threadIdx.x;
    const int wave = t >> 6, lane = t & 63;
    const int quad = lane >> 4, l16 = lane & 15;
    const int m0   = blockIdx.x * 128;
    const int n0   = blockIdx.y * 128;

    floatx4 acc[2][8];
#pragma unroll
    for (int mt = 0; mt < 2; ++mt)
#pragma unroll
        for (int nt = 0; nt < 8; ++nt)
            acc[mt][nt] = (floatx4){0.f, 0.f, 0.f, 0.f};

    for (int kt = 0; kt < D_IN; kt += 64) {
#pragma unroll
        for (int i = 0; i < 4; ++i) {
            int g = t + i * 256;          // 0..1023 (16B groups)
            int row = g >> 3, kq = g & 7;
            int grow = m0 + row;
            uint4 v = make_uint4(0u, 0u, 0u, 0u);
            if (grow < N_NODES)
                v = *(const uint4*)&Xb[(size_t)grow * D_IN + kt + kq * 8];
            *(uint4*)&As[row * PAD + kq * 8] = v;
        }
#pragma unroll
        for (int i = 0; i < 4; ++i) {
            int g = t + i * 256;
            int row = g >> 3, kq = g & 7;
            *(uint4*)&Bs[row * PAD + kq * 8] =
                *(const uint4*)&Wb[(size_t)(n0 + row) * D_IN + kt + kq * 8];
        }
        __syncthreads();

#pragma unroll
        for (int kk = 0; kk < 64; kk += 32) {
            bf16x8 a[2], b[8];
#pragma unroll
            for (int mt = 0; mt < 2; ++mt)
                a[mt] = *(bf16x8*)&As[(wave * 32 + mt * 16 + l16) * PAD + kk + quad * 8];
#pragma unroll
            for (int nt = 0; nt < 8; ++nt)
                b[nt] = *(bf16x8*)&Bs[(nt * 16 + l16) * PAD + kk + quad * 8];
#pragma unroll
            for (int mt = 0; mt < 2; ++mt)
#pragma unroll
                for (int nt = 0; nt < 8; ++nt)
                    acc[mt][nt] = __builtin_amdgcn_mfma_f32_16x16x32_bf16(
                        a[mt], b[nt], acc[mt][nt], 0, 0, 0);
        }
        __syncthreads();
    }

    if (blockIdx.y == 0) {
        float bb[8], sc[8], of[8];
#pragma unroll
        for (int nt = 0; nt < 8; ++nt) {
            bb[nt] = bias[nt * 16 + l16];
            sc[nt] = scale[nt * 16 + l16];
            of[nt] = offset[nt * 16 + l16];
        }
#pragma unroll
        for (int mt = 0; mt < 2; ++mt)
#pragma unroll
            for (int i = 0; i < 4; ++i) {
                float h[8], s = 0.f, q = 0.f;
#pragma unroll
                for (int nt = 0; nt < 8; ++nt) {
                    h[nt] = fmaxf(acc[mt][nt][i] + bb[nt], 0.f);
                    s += h[nt];
                    q += h[nt] * h[nt];
                }
#pragma unroll
                for (int m = 1; m < 16; m <<= 1) {
                    s += __shfl_xor(s, m);
                    q += __shfl_xor(q, m);
                }
                float mean = s * (1.f / 128.f);
                float inv  = rsqrtf(q * (1.f / 128.f) - mean * mean + EPS);
                int row = m0 + wave * 32 + mt * 16 + quad * 4 + i;
                if (row < N_NODES) {
#pragma unroll
                    for (int nt = 0; nt < 8; ++nt)
                        out[(size_t)row * 256 + nt * 16 + l16] =
                            (h[nt] - mean) * sc[nt] * inv + of[nt];
                }
            }
    } else {
#pragma unroll
        for (int mt = 0; mt < 2; ++mt)
#pragma unroll
            for (int i = 0; i < 4; ++i) {
                int row = m0 + wave * 32 + mt * 16 + quad * 4 + i;
                if (row < N_NODES) {
#pragma unroll
                    for (int nt = 0; nt < 8; ++nt)
                        Y1[(size_t)row * D_OUT + nt * 16 + l16] =
                            f2bf(acc[mt][nt][i]);
                }
            }
    }
}

// ---------------------------------------------------------------------------
// Fused gather-SpMM (bf16 Y) + bias + relu + LayerNorm -> out[:, 128:256].
// One wave per row; lane l owns cols {2l, 2l+1}. Edge loop unrolled x8 so
// 8 independent 256B row-gathers are in flight per wave (latency hiding).
// ---------------------------------------------------------------------------
__global__ __launch_bounds__(256) void spmm_gather_ln(
    const int* __restrict__ cnt, const int2* __restrict__ slot2,
    const ushort* __restrict__ Y,
    const float* __restrict__ bias, const float* __restrict__ scale,
    const float* __restrict__ offset, float* __restrict__ out)
{
    int row  = blockIdx.x * 4 + (threadIdx.x >> 6);
    int lane = threadIdx.x & 63;
    if (row >= N_NODES) return;

    int n = cnt[row * CNT_STRIDE];
    n = n < CAP ? n : CAP;

    int   c = 0;
    float v = 0.f;
    if (lane < n) {
        int2 p = slot2[(size_t)row * CAP + lane];
        c = p.x;
        v = __int_as_float(p.y);
    }

    float ax = 0.f, ay = 0.f;
    int j = 0;
    for (; j + 8 <= n; j += 8) {
        unsigned yv[8]; float vv[8];
#pragma unroll
        for (int u = 0; u < 8; ++u) {
            int cj = __shfl(c, j + u);
            vv[u]  = __shfl(v, j + u);
            yv[u]  = *(const unsigned*)&Y[(size_t)cj * D_OUT + lane * 2];
        }
#pragma unroll
        for (int u = 0; u < 8; ++u) {
            ax = fmaf(vv[u], __uint_as_float(yv[u] << 16), ax);
            ay = fmaf(vv[u], __uint_as_float(yv[u] & 0xffff0000u), ay);
        }
    }
    for (; j < n; ++j) {
        int   cj = __shfl(c, j);
        float vj = __shfl(v, j);
        unsigned yv = *(const unsigned*)&Y[(size_t)cj * D_OUT + lane * 2];
        ax = fmaf(vj, __uint_as_float(yv << 16), ax);
        ay = fmaf(vj, __uint_as_float(yv & 0xffff0000u), ay);
    }

    int cidx = lane * 2;
    float h0 = fmaxf(ax + bias[cidx + 0], 0.f);
    float h1 = fmaxf(ay + bias[cidx + 1], 0.f);
    float s = h0 + h1, q = h0 * h0 + h1 * h1;
#pragma unroll
    for (int m = 1; m < 64; m <<= 1) {
        s += __shfl_xor(s, m);
        q += __shfl_xor(q, m);
    }
    float mean = s * (1.f / 128.f);
    float var  = q * (1.f / 128.f) - mean * mean + EPS;
    float inv  = rsqrtf(var);
    float2 o;
    o.x = (h0 - mean) * scale[cidx + 0] * inv + offset[cidx + 0];
    o.y = (h1 - mean) * scale[cidx + 1] * inv + offset[cidx + 1];
    *(float2*)&out[(size_t)row * 256 + 128 + cidx] = o;
}

extern "C" void kernel_launch(void* const* d_in, const int* in_sizes, int n_in,
                              void* d_out, int out_size, void* d_ws, size_t ws_size,
                              hipStream_t stream)
{
    const float* feat = (const float*)d_in[0];
    const float* W0   = (const float*)d_in[1];
    const float* b0   = (const float*)d_in[2];
    const float* s0   = (const float*)d_in[3];
    const float* o0   = (const float*)d_in[4];
    const float* W1   = (const float*)d_in[5];
    const float* b1   = (const float*)d_in[6];
    const float* s1   = (const float*)d_in[7];
    const float* o1   = (const float*)d_in[8];
    const int*   er   = (const int*)d_in[9];
    const int*   ec   = (const int*)d_in[10];
    const float* ev   = (const float*)d_in[11];
    float* out = (float*)d_out;

    // workspace layout (all 16B-aligned offsets), total ~67.3 MB
    char*   wsb   = (char*)d_ws;
    ushort* Xb    = (ushort*)(wsb);                 // 25,600,000 B
    ushort* Wb    = (ushort*)(wsb + 25600000);      //    131,072 B
    ushort* Y1    = (ushort*)(wsb + 25731072);      // 12,800,000 B
    int*    cnt   = (int*)   (wsb + 38531072);      //  3,200,000 B (padded x16)
    int2*   slot2 = (int2*)  (wsb + 41731072);      // 25,600,000 B

    hipMemsetAsync(cnt, 0, (size_t)N_NODES * CNT_STRIDE * sizeof(int), stream);

    prep_build<<<BUILD_BLOCKS + PREP_XB_BLOCKS + PREP_WB_BLOCKS, 256, 0, stream>>>(
        feat, W0, W1, Xb, Wb, er, ec, ev, cnt, slot2);

    gemm_mfma<<<dim3((N_NODES + 127) / 128, 2), 256, 0, stream>>>(
        Xb, Wb, b0, s0, o0, out, Y1);

    spmm_gather_ln<<<(N_NODES + 3) / 4, 256, 0, stream>>>(
        cnt, slot2, Y1, b1, s1, o1, out);
}

// Round 7
// 213.707 us; speedup vs baseline: 1.1425x; 1.0199x over previous
//
#include <hip/hip_runtime.h>

#define N_NODES 50000
#define N_EDGES 800000
#define D_IN    256
#define D_OUT   128
#define EPS     1e-9f
#define CAP     64      // max edges/row (avg deg 16, Poisson tail P(>64) ~ 1e-19)
#define PAD     88      // LDS k-stride in ushorts: 176B rows, 16B-aligned b128

#define SCATTER_BLOCKS 196   // 196 * 4096 = 802816 >= 800000 edges
#define GEMM_MBLKS     391   // ceil(50000/128)

typedef __attribute__((ext_vector_type(8))) short bf16x8;   // MFMA A/B frag (4 VGPRs)
typedef __attribute__((ext_vector_type(4))) float floatx4;  // MFMA C/D frag

__device__ __forceinline__ ushort f2bf(float x) {           // RTNE fp32 -> bf16
    unsigned u = __float_as_uint(x);
    u += 0x7fffu + ((u >> 16) & 1u);
    return (ushort)(u >> 16);
}

// ---------------------------------------------------------------------------
// prep: (a) Xb = bf16(feat) [50000x256]  (b) Wb[n][k] = bf16 transposed [W0|W1]
// ---------------------------------------------------------------------------
#define PREP_XB_BLOCKS  6250   // 12.8M elems / (256 thr * 8 elem)
#define PREP_WB_BLOCKS  32
__global__ __launch_bounds__(256) void prep(
    const float* __restrict__ feat, const float* __restrict__ W0,
    const float* __restrict__ W1, ushort* __restrict__ Xb,
    ushort* __restrict__ Wb)
{
    int bid = blockIdx.x;
    int t   = threadIdx.x;
    if (bid < PREP_XB_BLOCKS) {
        size_t g = (size_t)bid * 256 + t;       // 8-elem group
        const float* p = &feat[g * 8];
        float4 v0 = *(const float4*)p;
        float4 v1 = *(const float4*)(p + 4);
        union { ushort us[8]; uint4 v; } tmp;
        tmp.us[0] = f2bf(v0.x); tmp.us[1] = f2bf(v0.y);
        tmp.us[2] = f2bf(v0.z); tmp.us[3] = f2bf(v0.w);
        tmp.us[4] = f2bf(v1.x); tmp.us[5] = f2bf(v1.y);
        tmp.us[6] = f2bf(v1.z); tmp.us[7] = f2bf(v1.w);
        *(uint4*)&Xb[g * 8] = tmp.v;
    } else {
        int g  = (bid - PREP_XB_BLOCKS) * 256 + t;
        int n  = g >> 5;                        // 0..255
        int kq = g & 31;                        // 8-elem k group
        const float* W = (n < 128) ? W0 : W1;
        int nn = n & 127;
        union { ushort us[8]; uint4 v; } tmp;
#pragma unroll
        for (int j = 0; j < 8; ++j)
            tmp.us[j] = f2bf(W[(size_t)(kq * 8 + j) * D_OUT + nn]);
        *(uint4*)&Wb[(size_t)n * D_IN + kq * 8] = tmp.v;
    }
}

// ---------------------------------------------------------------------------
// Fused kernel, BLOCK-role split (not thread-prologue: R5 showed the K-loop
// barrier's vmcnt(0) drain serializes a per-thread scatter; separate blocks
// have no shared barrier, so scatter's atomic latency hides under other
// blocks' MFMA — m114 co-scheduling).
//   bid < SCATTER_BLOCKS: scatter 4096 edges into (cnt, slot2); no barrier,
//     16 independent atomic chains per thread. Dispatched FIRST so these
//     blocks co-reside with the first gemm blocks.
//   else: 128x128 bf16 MFMA gemm tile, BK=64, 4 waves.
//     half 0 (n0=0):   cols 0..127  -> bias0+relu+LN -> out[:, 0:128]
//     half 1 (n0=128): cols 128..255 -> raw bf16 -> Y1[M,128]
// launch_bounds (256,3): LDS 3x45056 <= 160K -> a scatter block never evicts
// a gemm block (2 gemm + 1 scatter per CU).
// 16x16x32 layouts (HW-verified): A[m=lane&15][k=quad*8+j],
// B[k=quad*8+j][n=lane&15], D[row=quad*4+reg][col=lane&15].
// ---------------------------------------------------------------------------
__global__ __launch_bounds__(256, 3) void gemm_scatter(
    const ushort* __restrict__ Xb, const ushort* __restrict__ Wb,
    const float* __restrict__ bias, const float* __restrict__ scale,
    const float* __restrict__ offset,
    float* __restrict__ out, ushort* __restrict__ Y1,
    const int* __restrict__ er, const int* __restrict__ ec,
    const float* __restrict__ ev, int* __restrict__ cnt,
    int2* __restrict__ slot2)
{
    __shared__ ushort As[128 * PAD];
    __shared__ ushort Bs[128 * PAD];

    const int t = threadIdx.x;

    if (blockIdx.x < SCATTER_BLOCKS) {
        int ebase = blockIdx.x * 4096;
        int   rr[16], cc[16];
        float vv[16];
#pragma unroll
        for (int u = 0; u < 16; ++u) {
            int e = ebase + u * 256 + t;
            bool ok = (e < N_EDGES);
            rr[u] = ok ? er[e] : -1;
            cc[u] = ok ? ec[e] : 0;
            vv[u] = ok ? ev[e] : 0.f;
        }
#pragma unroll
        for (int u = 0; u < 16; ++u) {
            if (rr[u] >= 0) {
                int pos = atomicAdd(&cnt[rr[u]], 1);
                if (pos < CAP)
                    slot2[(size_t)rr[u] * CAP + pos] =
                        make_int2(cc[u], __float_as_int(vv[u]));
            }
        }
        return;
    }

    const int gbid = blockIdx.x - SCATTER_BLOCKS;       // 0..781
    const int half = gbid / GEMM_MBLKS;                 // 0 or 1
    const int mblk = gbid % GEMM_MBLKS;
    const int wave = t >> 6, lane = t & 63;
    const int quad = lane >> 4, l16 = lane & 15;
    const int m0   = mblk * 128;
    const int n0   = half * 128;

    floatx4 acc[2][8];
#pragma unroll
    for (int mt = 0; mt < 2; ++mt)
#pragma unroll
        for (int nt = 0; nt < 8; ++nt)
            acc[mt][nt] = (floatx4){0.f, 0.f, 0.f, 0.f};

    for (int kt = 0; kt < D_IN; kt += 64) {
#pragma unroll
        for (int i = 0; i < 4; ++i) {
            int g = t + i * 256;          // 0..1023 (16B groups)
            int row = g >> 3, kq = g & 7;
            int grow = m0 + row;
            uint4 v = make_uint4(0u, 0u, 0u, 0u);
            if (grow < N_NODES)
                v = *(const uint4*)&Xb[(size_t)grow * D_IN + kt + kq * 8];
            *(uint4*)&As[row * PAD + kq * 8] = v;
        }
#pragma unroll
        for (int i = 0; i < 4; ++i) {
            int g = t + i * 256;
            int row = g >> 3, kq = g & 7;
            *(uint4*)&Bs[row * PAD + kq * 8] =
                *(const uint4*)&Wb[(size_t)(n0 + row) * D_IN + kt + kq * 8];
        }
        __syncthreads();

#pragma unroll
        for (int kk = 0; kk < 64; kk += 32) {
            bf16x8 a[2], b[8];
#pragma unroll
            for (int mt = 0; mt < 2; ++mt)
                a[mt] = *(bf16x8*)&As[(wave * 32 + mt * 16 + l16) * PAD + kk + quad * 8];
#pragma unroll
            for (int nt = 0; nt < 8; ++nt)
                b[nt] = *(bf16x8*)&Bs[(nt * 16 + l16) * PAD + kk + quad * 8];
#pragma unroll
            for (int mt = 0; mt < 2; ++mt)
#pragma unroll
                for (int nt = 0; nt < 8; ++nt)
                    acc[mt][nt] = __builtin_amdgcn_mfma_f32_16x16x32_bf16(
                        a[mt], b[nt], acc[mt][nt], 0, 0, 0);
        }
        __syncthreads();
    }

    if (half == 0) {
        float bb[8], sc[8], of[8];
#pragma unroll
        for (int nt = 0; nt < 8; ++nt) {
            bb[nt] = bias[nt * 16 + l16];
            sc[nt] = scale[nt * 16 + l16];
            of[nt] = offset[nt * 16 + l16];
        }
#pragma unroll
        for (int mt = 0; mt < 2; ++mt)
#pragma unroll
            for (int i = 0; i < 4; ++i) {
                float h[8], s = 0.f, q = 0.f;
#pragma unroll
                for (int nt = 0; nt < 8; ++nt) {
                    h[nt] = fmaxf(acc[mt][nt][i] + bb[nt], 0.f);
                    s += h[nt];
                    q += h[nt] * h[nt];
                }
#pragma unroll
                for (int m = 1; m < 16; m <<= 1) {
                    s += __shfl_xor(s, m);
                    q += __shfl_xor(q, m);
                }
                float mean = s * (1.f / 128.f);
                float inv  = rsqrtf(q * (1.f / 128.f) - mean * mean + EPS);
                int row = m0 + wave * 32 + mt * 16 + quad * 4 + i;
                if (row < N_NODES) {
#pragma unroll
                    for (int nt = 0; nt < 8; ++nt)
                        out[(size_t)row * 256 + nt * 16 + l16] =
                            (h[nt] - mean) * sc[nt] * inv + of[nt];
                }
            }
    } else {
#pragma unroll
        for (int mt = 0; mt < 2; ++mt)
#pragma unroll
            for (int i = 0; i < 4; ++i) {
                int row = m0 + wave * 32 + mt * 16 + quad * 4 + i;
                if (row < N_NODES) {
#pragma unroll
                    for (int nt = 0; nt < 8; ++nt)
                        Y1[(size_t)row * D_OUT + nt * 16 + l16] =
                            f2bf(acc[mt][nt][i]);
                }
            }
    }
}

// ---------------------------------------------------------------------------
// Fused gather-SpMM (bf16 Y) + bias + relu + LayerNorm -> out[:, 128:256].
// One wave per row; lane l owns cols {2l, 2l+1}. Edge loop unrolled x8 so
// 8 independent 256B row-gathers are in flight per wave (latency hiding).
// ---------------------------------------------------------------------------
__global__ __launch_bounds__(256) void spmm_gather_ln(
    const int* __restrict__ cnt, const int2* __restrict__ slot2,
    const ushort* __restrict__ Y,
    const float* __restrict__ bias, const float* __restrict__ scale,
    const float* __restrict__ offset, float* __restrict__ out)
{
    int row  = blockIdx.x * 4 + (threadIdx.x >> 6);
    int lane = threadIdx.x & 63;
    if (row >= N_NODES) return;

    int n = cnt[row];
    n = n < CAP ? n : CAP;

    int   c = 0;
    float v = 0.f;
    if (lane < n) {
        int2 p = slot2[(size_t)row * CAP + lane];
        c = p.x;
        v = __int_as_float(p.y);
    }

    float ax = 0.f, ay = 0.f;
    int j = 0;
    for (; j + 8 <= n; j += 8) {
        unsigned yv[8]; float vv[8];
#pragma unroll
        for (int u = 0; u < 8; ++u) {
            int cj = __shfl(c, j + u);
            vv[u]  = __shfl(v, j + u);
            yv[u]  = *(const unsigned*)&Y[(size_t)cj * D_OUT + lane * 2];
        }
#pragma unroll
        for (int u = 0; u < 8; ++u) {
            ax = fmaf(vv[u], __uint_as_float(yv[u] << 16), ax);
            ay = fmaf(vv[u], __uint_as_float(yv[u] & 0xffff0000u), ay);
        }
    }
    for (; j < n; ++j) {
        int   cj = __shfl(c, j);
        float vj = __shfl(v, j);
        unsigned yv = *(const unsigned*)&Y[(size_t)cj * D_OUT + lane * 2];
        ax = fmaf(vj, __uint_as_float(yv << 16), ax);
        ay = fmaf(vj, __uint_as_float(yv & 0xffff0000u), ay);
    }

    int cidx = lane * 2;
    float h0 = fmaxf(ax + bias[cidx + 0], 0.f);
    float h1 = fmaxf(ay + bias[cidx + 1], 0.f);
    float s = h0 + h1, q = h0 * h0 + h1 * h1;
#pragma unroll
    for (int m = 1; m < 64; m <<= 1) {
        s += __shfl_xor(s, m);
        q += __shfl_xor(q, m);
    }
    float mean = s * (1.f / 128.f);
    float var  = q * (1.f / 128.f) - mean * mean + EPS;
    float inv  = rsqrtf(var);
    float2 o;
    o.x = (h0 - mean) * scale[cidx + 0] * inv + offset[cidx + 0];
    o.y = (h1 - mean) * scale[cidx + 1] * inv + offset[cidx + 1];
    *(float2*)&out[(size_t)row * 256 + 128 + cidx] = o;
}

extern "C" void kernel_launch(void* const* d_in, const int* in_sizes, int n_in,
                              void* d_out, int out_size, void* d_ws, size_t ws_size,
                              hipStream_t stream)
{
    const float* feat = (const float*)d_in[0];
    const float* W0   = (const float*)d_in[1];
    const float* b0   = (const float*)d_in[2];
    const float* s0   = (const float*)d_in[3];
    const float* o0   = (const float*)d_in[4];
    const float* W1   = (const float*)d_in[5];
    const float* b1   = (const float*)d_in[6];
    const float* s1   = (const float*)d_in[7];
    const float* o1   = (const float*)d_in[8];
    const int*   er   = (const int*)d_in[9];
    const int*   ec   = (const int*)d_in[10];
    const float* ev   = (const float*)d_in[11];
    float* out = (float*)d_out;

    // workspace layout (all 16B-aligned offsets), total ~64.3 MB
    char*   wsb   = (char*)d_ws;
    ushort* Xb    = (ushort*)(wsb);                 // 25,600,000 B
    ushort* Wb    = (ushort*)(wsb + 25600000);      //    131,072 B
    ushort* Y1    = (ushort*)(wsb + 25731072);      // 12,800,000 B
    int*    cnt   = (int*)   (wsb + 38531072);      //    200,000 B
    int2*   slot2 = (int2*)  (wsb + 38731072);      // 25,600,000 B

    hipMemsetAsync(cnt, 0, (size_t)N_NODES * sizeof(int), stream);

    prep<<<PREP_XB_BLOCKS + PREP_WB_BLOCKS, 256, 0, stream>>>(
        feat, W0, W1, Xb, Wb);

    gemm_scatter<<<SCATTER_BLOCKS + 2 * GEMM_MBLKS, 256, 0, stream>>>(
        Xb, Wb, b0, s0, o0, out, Y1, er, ec, ev, cnt, slot2);

    spmm_gather_ln<<<(N_NODES + 3) / 4, 256, 0, stream>>>(
        cnt, slot2, Y1, b1, s1, o1, out);
}

// Round 8
// 209.451 us; speedup vs baseline: 1.1657x; 1.0203x over previous
//
#include <hip/hip_runtime.h>

#define N_NODES 50000
#define N_EDGES 800000
#define D_IN    256
#define D_OUT   128
#define EPS     1e-9f
#define CAP     64      // max edges/row (avg deg 16, Poisson tail P(>64) ~ 1e-19)
#define PAD     88      // LDS k-stride in ushorts: 176B rows, 16B-aligned b128

#define SCATTER_BLOCKS 196   // 196 * 4096 = 802816 >= 800000 edges
#define GEMM_MBLKS     391   // ceil(50000/128)

typedef __attribute__((ext_vector_type(8))) short bf16x8;   // MFMA A/B frag (4 VGPRs)
typedef __attribute__((ext_vector_type(4))) float floatx4;  // MFMA C/D frag

__device__ __forceinline__ ushort f2bf(float x) {           // RTNE fp32 -> bf16
    unsigned u = __float_as_uint(x);
    u += 0x7fffu + ((u >> 16) & 1u);
    return (ushort)(u >> 16);
}

// ---------------------------------------------------------------------------
// prep_small: (a) cnt = 0  (b) Wb[n][k] = bf16 transposed [W0|W1].
// Tiny (~4 us). Xb conversion is gone — gemm converts feat in-staging.
// ---------------------------------------------------------------------------
#define CNT_BLOCKS 49         // 12500 int4 / 256
#define WB_BLOCKS  32
__global__ __launch_bounds__(256) void prep_small(
    const float* __restrict__ W0, const float* __restrict__ W1,
    ushort* __restrict__ Wb, int* __restrict__ cnt)
{
    int bid = blockIdx.x;
    int t   = threadIdx.x;
    if (bid < CNT_BLOCKS) {
        int idx4 = bid * 256 + t;             // int4 index
        if (idx4 < 12500)
            *(int4*)&cnt[idx4 * 4] = make_int4(0, 0, 0, 0);
    } else {
        int g  = (bid - CNT_BLOCKS) * 256 + t;
        int n  = g >> 5;                      // 0..255
        int kq = g & 31;                      // 8-elem k group
        const float* W = (n < 128) ? W0 : W1;
        int nn = n & 127;
        union { ushort us[8]; uint4 v; } tmp;
#pragma unroll
        for (int j = 0; j < 8; ++j)
            tmp.us[j] = f2bf(W[(size_t)(kq * 8 + j) * D_OUT + nn]);
        *(uint4*)&Wb[(size_t)n * D_IN + kq * 8] = tmp.v;
    }
}

// ---------------------------------------------------------------------------
// Fused kernel, BLOCK-role split (R5 showed thread-prologue fusion serializes
// at the K-loop barrier's vmcnt(0) drain; separate scatter blocks have no
// barrier, so their atomic latency hides under other blocks' MFMA — m114).
//   bid < SCATTER_BLOCKS: scatter 4096 edges into (cnt, slot2); no barrier,
//     16 independent atomic chains per thread. Random-line atomics run at
//     ~15 G line-ops/s (measured R6/R7) -> ~53 us; this IS the kernel's
//     critical path, the gemm blocks ride in its shadow.
//   else: 128x128 bf16 MFMA gemm tile, BK=64, 4 waves; A-staging converts
//     feat fp32->bf16 on the fly (no Xb buffer).
//     half 0 (n0=0):   cols 0..127  -> bias0+relu+LN -> out[:, 0:128]
//     half 1 (n0=128): cols 128..255 -> raw bf16 -> Y1[M,128]
// 16x16x32 layouts (HW-verified): A[m=lane&15][k=quad*8+j],
// B[k=quad*8+j][n=lane&15], D[row=quad*4+reg][col=lane&15].
// ---------------------------------------------------------------------------
__global__ __launch_bounds__(256, 3) void gemm_scatter(
    const float* __restrict__ feat, const ushort* __restrict__ Wb,
    const float* __restrict__ bias, const float* __restrict__ scale,
    const float* __restrict__ offset,
    float* __restrict__ out, ushort* __restrict__ Y1,
    const int* __restrict__ er, const int* __restrict__ ec,
    const float* __restrict__ ev, int* __restrict__ cnt,
    int2* __restrict__ slot2)
{
    __shared__ ushort As[128 * PAD];
    __shared__ ushort Bs[128 * PAD];

    const int t = threadIdx.x;

    if (blockIdx.x < SCATTER_BLOCKS) {
        int ebase = blockIdx.x * 4096;
        int   rr[16], cc[16];
        float vv[16];
#pragma unroll
        for (int u = 0; u < 16; ++u) {
            int e = ebase + u * 256 + t;
            bool ok = (e < N_EDGES);
            rr[u] = ok ? er[e] : -1;
            cc[u] = ok ? ec[e] : 0;
            vv[u] = ok ? ev[e] : 0.f;
        }
#pragma unroll
        for (int u = 0; u < 16; ++u) {
            if (rr[u] >= 0) {
                int pos = atomicAdd(&cnt[rr[u]], 1);
                if (pos < CAP)
                    slot2[(size_t)rr[u] * CAP + pos] =
                        make_int2(cc[u], __float_as_int(vv[u]));
            }
        }
        return;
    }

    const int gbid = blockIdx.x - SCATTER_BLOCKS;       // 0..781
    const int half = gbid / GEMM_MBLKS;                 // 0 or 1
    const int mblk = gbid % GEMM_MBLKS;
    const int wave = t >> 6, lane = t & 63;
    const int quad = lane >> 4, l16 = lane & 15;
    const int m0   = mblk * 128;
    const int n0   = half * 128;

    floatx4 acc[2][8];
#pragma unroll
    for (int mt = 0; mt < 2; ++mt)
#pragma unroll
        for (int nt = 0; nt < 8; ++nt)
            acc[mt][nt] = (floatx4){0.f, 0.f, 0.f, 0.f};

    for (int kt = 0; kt < D_IN; kt += 64) {
        // ---- stage A (128 rows x 64 k), fp32 feat -> bf16 on the fly ----
#pragma unroll
        for (int i = 0; i < 4; ++i) {
            int g = t + i * 256;          // 0..1023 (8-elem groups)
            int row = g >> 3, kq = g & 7;
            int grow = m0 + row;
            union { ushort us[8]; uint4 v; } tmp;
            tmp.v = make_uint4(0u, 0u, 0u, 0u);
            if (grow < N_NODES) {
                const float* p = &feat[(size_t)grow * D_IN + kt + kq * 8];
                float4 v0 = *(const float4*)p;
                float4 v1 = *(const float4*)(p + 4);
                tmp.us[0] = f2bf(v0.x); tmp.us[1] = f2bf(v0.y);
                tmp.us[2] = f2bf(v0.z); tmp.us[3] = f2bf(v0.w);
                tmp.us[4] = f2bf(v1.x); tmp.us[5] = f2bf(v1.y);
                tmp.us[6] = f2bf(v1.z); tmp.us[7] = f2bf(v1.w);
            }
            *(uint4*)&As[row * PAD + kq * 8] = tmp.v;
        }
        // ---- stage B (128 n-rows x 64 k) from Wb[n][k] ----
#pragma unroll
        for (int i = 0; i < 4; ++i) {
            int g = t + i * 256;
            int row = g >> 3, kq = g & 7;
            *(uint4*)&Bs[row * PAD + kq * 8] =
                *(const uint4*)&Wb[(size_t)(n0 + row) * D_IN + kt + kq * 8];
        }
        __syncthreads();

#pragma unroll
        for (int kk = 0; kk < 64; kk += 32) {
            bf16x8 a[2], b[8];
#pragma unroll
            for (int mt = 0; mt < 2; ++mt)
                a[mt] = *(bf16x8*)&As[(wave * 32 + mt * 16 + l16) * PAD + kk + quad * 8];
#pragma unroll
            for (int nt = 0; nt < 8; ++nt)
                b[nt] = *(bf16x8*)&Bs[(nt * 16 + l16) * PAD + kk + quad * 8];
#pragma unroll
            for (int mt = 0; mt < 2; ++mt)
#pragma unroll
                for (int nt = 0; nt < 8; ++nt)
                    acc[mt][nt] = __builtin_amdgcn_mfma_f32_16x16x32_bf16(
                        a[mt], b[nt], acc[mt][nt], 0, 0, 0);
        }
        __syncthreads();
    }

    if (half == 0) {
        float bb[8], sc[8], of[8];
#pragma unroll
        for (int nt = 0; nt < 8; ++nt) {
            bb[nt] = bias[nt * 16 + l16];
            sc[nt] = scale[nt * 16 + l16];
            of[nt] = offset[nt * 16 + l16];
        }
#pragma unroll
        for (int mt = 0; mt < 2; ++mt)
#pragma unroll
            for (int i = 0; i < 4; ++i) {
                float h[8], s = 0.f, q = 0.f;
#pragma unroll
                for (int nt = 0; nt < 8; ++nt) {
                    h[nt] = fmaxf(acc[mt][nt][i] + bb[nt], 0.f);
                    s += h[nt];
                    q += h[nt] * h[nt];
                }
#pragma unroll
                for (int m = 1; m < 16; m <<= 1) {
                    s += __shfl_xor(s, m);
                    q += __shfl_xor(q, m);
                }
                float mean = s * (1.f / 128.f);
                float inv  = rsqrtf(q * (1.f / 128.f) - mean * mean + EPS);
                int row = m0 + wave * 32 + mt * 16 + quad * 4 + i;
                if (row < N_NODES) {
#pragma unroll
                    for (int nt = 0; nt < 8; ++nt)
                        out[(size_t)row * 256 + nt * 16 + l16] =
                            (h[nt] - mean) * sc[nt] * inv + of[nt];
                }
            }
    } else {
#pragma unroll
        for (int mt = 0; mt < 2; ++mt)
#pragma unroll
            for (int i = 0; i < 4; ++i) {
                int row = m0 + wave * 32 + mt * 16 + quad * 4 + i;
                if (row < N_NODES) {
#pragma unroll
                    for (int nt = 0; nt < 8; ++nt)
                        Y1[(size_t)row * D_OUT + nt * 16 + l16] =
                            f2bf(acc[mt][nt][i]);
                }
            }
    }
}

// ---------------------------------------------------------------------------
// Fused gather-SpMM (bf16 Y) + bias + relu + LayerNorm -> out[:, 128:256].
// One wave per row; lane l owns cols {2l, 2l+1}. Edge loop unrolled x8 so
// 8 independent 256B row-gathers are in flight per wave (latency hiding).
// ---------------------------------------------------------------------------
__global__ __launch_bounds__(256) void spmm_gather_ln(
    const int* __restrict__ cnt, const int2* __restrict__ slot2,
    const ushort* __restrict__ Y,
    const float* __restrict__ bias, const float* __restrict__ scale,
    const float* __restrict__ offset, float* __restrict__ out)
{
    int row  = blockIdx.x * 4 + (threadIdx.x >> 6);
    int lane = threadIdx.x & 63;
    if (row >= N_NODES) return;

    int n = cnt[row];
    n = n < CAP ? n : CAP;

    int   c = 0;
    float v = 0.f;
    if (lane < n) {
        int2 p = slot2[(size_t)row * CAP + lane];
        c = p.x;
        v = __int_as_float(p.y);
    }

    float ax = 0.f, ay = 0.f;
    int j = 0;
    for (; j + 8 <= n; j += 8) {
        unsigned yv[8]; float vv[8];
#pragma unroll
        for (int u = 0; u < 8; ++u) {
            int cj = __shfl(c, j + u);
            vv[u]  = __shfl(v, j + u);
            yv[u]  = *(const unsigned*)&Y[(size_t)cj * D_OUT + lane * 2];
        }
#pragma unroll
        for (int u = 0; u < 8; ++u) {
            ax = fmaf(vv[u], __uint_as_float(yv[u] << 16), ax);
            ay = fmaf(vv[u], __uint_as_float(yv[u] & 0xffff0000u), ay);
        }
    }
    for (; j < n; ++j) {
        int   cj = __shfl(c, j);
        float vj = __shfl(v, j);
        unsigned yv = *(const unsigned*)&Y[(size_t)cj * D_OUT + lane * 2];
        ax = fmaf(vj, __uint_as_float(yv << 16), ax);
        ay = fmaf(vj, __uint_as_float(yv & 0xffff0000u), ay);
    }

    int cidx = lane * 2;
    float h0 = fmaxf(ax + bias[cidx + 0], 0.f);
    float h1 = fmaxf(ay + bias[cidx + 1], 0.f);
    float s = h0 + h1, q = h0 * h0 + h1 * h1;
#pragma unroll
    for (int m = 1; m < 64; m <<= 1) {
        s += __shfl_xor(s, m);
        q += __shfl_xor(q, m);
    }
    float mean = s * (1.f / 128.f);
    float var  = q * (1.f / 128.f) - mean * mean + EPS;
    float inv  = rsqrtf(var);
    float2 o;
    o.x = (h0 - mean) * scale[cidx + 0] * inv + offset[cidx + 0];
    o.y = (h1 - mean) * scale[cidx + 1] * inv + offset[cidx + 1];
    *(float2*)&out[(size_t)row * 256 + 128 + cidx] = o;
}

extern "C" void kernel_launch(void* const* d_in, const int* in_sizes, int n_in,
                              void* d_out, int out_size, void* d_ws, size_t ws_size,
                              hipStream_t stream)
{
    const float* feat = (const float*)d_in[0];
    const float* W0   = (const float*)d_in[1];
    const float* b0   = (const float*)d_in[2];
    const float* s0   = (const float*)d_in[3];
    const float* o0   = (const float*)d_in[4];
    const float* W1   = (const float*)d_in[5];
    const float* b1   = (const float*)d_in[6];
    const float* s1   = (const float*)d_in[7];
    const float* o1   = (const float*)d_in[8];
    const int*   er   = (const int*)d_in[9];
    const int*   ec   = (const int*)d_in[10];
    const float* ev   = (const float*)d_in[11];
    float* out = (float*)d_out;

    // workspace layout (16B-aligned offsets), total ~38.7 MB
    char*   wsb   = (char*)d_ws;
    ushort* Wb    = (ushort*)(wsb);                 //    131,072 B
    ushort* Y1    = (ushort*)(wsb + 131072);        // 12,800,000 B
    int*    cnt   = (int*)   (wsb + 12931072);      //    200,000 B
    int2*   slot2 = (int2*)  (wsb + 13131072);      // 25,600,000 B

    prep_small<<<CNT_BLOCKS + WB_BLOCKS, 256, 0, stream>>>(W0, W1, Wb, cnt);

    gemm_scatter<<<SCATTER_BLOCKS + 2 * GEMM_MBLKS, 256, 0, stream>>>(
        feat, Wb, b0, s0, o0, out, Y1, er, ec, ev, cnt, slot2);

    spmm_gather_ln<<<(N_NODES + 3) / 4, 256, 0, stream>>>(
        cnt, slot2, Y1, b1, s1, o1, out);
}